// Round 1
// baseline (1175.698 us; speedup 1.0000x reference)
//
#include <hip/hip_runtime.h>
#include <math.h>

#define N_ROWS 100000
#define NG     2000
#define M0     256
#define M1     128
#define DIMX   640
#define EPSV   1e-5f
#define TM     16

#define INV_SQRT3 0.57735026918962576f
#define INV_SQRT2 0.70710678118654752f

__device__ __forceinline__ int lower_bound_i(const int* __restrict__ b, int n, int key) {
    int lo = 0, hi = n;
    while (lo < hi) { int m = (lo + hi) >> 1; if (b[m] < key) lo = m + 1; else hi = m; }
    return lo;
}

// ---------------------------------------------------------------------------
// Kernel 1: per-row tensor product -> pre-norm out0|out1 written to d_out.
// Block: 256 threads = 64 col-threads (cw) x 4 row-groups (rg); 16 rows/block.
// Each thread: 4 rows x (4 cols of out0 + 2 cols of out1 x 3 components).
// ---------------------------------------------------------------------------
__global__ __launch_bounds__(256, 2)
void k1_compute(const float* __restrict__ x, const float* __restrict__ y,
                const float* __restrict__ w000, const float* __restrict__ w011,
                const float* __restrict__ w101, const float* __restrict__ w110,
                const float* __restrict__ w111, const float* __restrict__ bias0,
                float* __restrict__ out)
{
    __shared__ float sS1[TM][M0];       // 16 KB  s1
    __shared__ float sVD[TM][M1][4];    // 32 KB  v1.xyz, d = v1 . v2
    __shared__ float sCX[TM][M1];       // 8 KB   cross.x
    __shared__ float sCY[TM][M1];       // 8 KB
    __shared__ float sCZ[TM][M1];       // 8 KB
    __shared__ float sY[TM][4];         // s2, v2.xyz

    const int t  = threadIdx.x;
    const int n0 = blockIdx.x * TM;

    if (t < TM * 4) {
        int r = t >> 2, c = t & 3;
        sY[r][c] = y[(n0 + r) * 4 + c];
    }
    // s1: 16 rows x 256 = 4096 floats, coalesced
    #pragma unroll
    for (int i = 0; i < (TM * M0) / 256; ++i) {
        int idx = t + 256 * i;
        int r = idx >> 8, c = idx & 255;
        sS1[r][c] = x[(size_t)(n0 + r) * DIMX + c];
    }
    __syncthreads();
    // v1, d, cross: 16 rows x 128 u
    #pragma unroll
    for (int i = 0; i < (TM * M1) / 256; ++i) {
        int p = t + 256 * i;
        int r = p >> 7, u = p & 127;
        const float* vp = x + (size_t)(n0 + r) * DIMX + M0 + u * 3;
        float vx = vp[0], vy = vp[1], vz = vp[2];
        float v2x = sY[r][1], v2y = sY[r][2], v2z = sY[r][3];
        sVD[r][u][0] = vx; sVD[r][u][1] = vy; sVD[r][u][2] = vz;
        sVD[r][u][3] = vx * v2x + vy * v2y + vz * v2z;
        sCX[r][u] = vy * v2z - vz * v2y;
        sCY[r][u] = vz * v2x - vx * v2z;
        sCZ[r][u] = vx * v2y - vy * v2x;
    }
    __syncthreads();

    const int cw = t & 63;   // column thread
    const int rg = t >> 6;   // row group (4 rows each)

    float accS[4][4] = {};      // s1 @ W000          -> out0
    float accD[4][4] = {};      // d  @ W110          -> out0
    float accA[4][2] = {};      // s1 @ W011          -> out1 (x v2[k])
    float accB[4][3][2] = {};   // v1_k @ W101        -> out1 (x s2)
    float accC[4][3][2] = {};   // cross_k @ W111     -> out1 (x 1/sqrt2)

    const float* w0p = w000 + cw * 4;
    const float* w1p = w011 + cw * 2;
    for (int u = 0; u < M0; ++u) {
        float4 w0 = *(const float4*)(w0p + (size_t)u * M0);
        float2 w1 = *(const float2*)(w1p + (size_t)u * M1);
        #pragma unroll
        for (int i = 0; i < 4; ++i) {
            float a = sS1[rg * 4 + i][u];
            accS[i][0] = fmaf(a, w0.x, accS[i][0]);
            accS[i][1] = fmaf(a, w0.y, accS[i][1]);
            accS[i][2] = fmaf(a, w0.z, accS[i][2]);
            accS[i][3] = fmaf(a, w0.w, accS[i][3]);
            accA[i][0] = fmaf(a, w1.x, accA[i][0]);
            accA[i][1] = fmaf(a, w1.y, accA[i][1]);
        }
    }

    const float* wDp = w110 + cw * 4;
    const float* wBp = w101 + cw * 2;
    const float* wCp = w111 + cw * 2;
    for (int u = 0; u < M1; ++u) {
        float4 wD = *(const float4*)(wDp + (size_t)u * M0);
        float2 wB = *(const float2*)(wBp + (size_t)u * M1);
        float2 wC = *(const float2*)(wCp + (size_t)u * M1);
        #pragma unroll
        for (int i = 0; i < 4; ++i) {
            int r = rg * 4 + i;
            float4 vd = *(const float4*)&sVD[r][u][0];
            float cx = sCX[r][u], cy = sCY[r][u], cz = sCZ[r][u];
            accD[i][0] = fmaf(vd.w, wD.x, accD[i][0]);
            accD[i][1] = fmaf(vd.w, wD.y, accD[i][1]);
            accD[i][2] = fmaf(vd.w, wD.z, accD[i][2]);
            accD[i][3] = fmaf(vd.w, wD.w, accD[i][3]);
            accB[i][0][0] = fmaf(vd.x, wB.x, accB[i][0][0]);
            accB[i][0][1] = fmaf(vd.x, wB.y, accB[i][0][1]);
            accB[i][1][0] = fmaf(vd.y, wB.x, accB[i][1][0]);
            accB[i][1][1] = fmaf(vd.y, wB.y, accB[i][1][1]);
            accB[i][2][0] = fmaf(vd.z, wB.x, accB[i][2][0]);
            accB[i][2][1] = fmaf(vd.z, wB.y, accB[i][2][1]);
            accC[i][0][0] = fmaf(cx, wC.x, accC[i][0][0]);
            accC[i][0][1] = fmaf(cx, wC.y, accC[i][0][1]);
            accC[i][1][0] = fmaf(cy, wC.x, accC[i][1][0]);
            accC[i][1][1] = fmaf(cy, wC.y, accC[i][1][1]);
            accC[i][2][0] = fmaf(cz, wC.x, accC[i][2][0]);
            accC[i][2][1] = fmaf(cz, wC.y, accC[i][2][1]);
        }
    }

    const float4 b0 = *(const float4*)(bias0 + cw * 4);
    #pragma unroll
    for (int i = 0; i < 4; ++i) {
        int r = rg * 4 + i;
        int n = n0 + r;
        float s2  = sY[r][0];
        float v2a[3] = { sY[r][1], sY[r][2], sY[r][3] };
        float* orow = out + (size_t)n * DIMX;

        float4 o0;
        o0.x = fmaf(s2, accS[i][0], fmaf(INV_SQRT3, accD[i][0], b0.x));
        o0.y = fmaf(s2, accS[i][1], fmaf(INV_SQRT3, accD[i][1], b0.y));
        o0.z = fmaf(s2, accS[i][2], fmaf(INV_SQRT3, accD[i][2], b0.z));
        o0.w = fmaf(s2, accS[i][3], fmaf(INV_SQRT3, accD[i][3], b0.w));
        *(float4*)(orow + cw * 4) = o0;

        float o1[6];
        #pragma unroll
        for (int c = 0; c < 2; ++c) {
            #pragma unroll
            for (int k = 0; k < 3; ++k) {
                o1[c * 3 + k] = fmaf(accA[i][c], v2a[k],
                                 fmaf(s2, accB[i][k][c],
                                      INV_SQRT2 * accC[i][k][c]));
            }
        }
        float* o1p = orow + M0 + cw * 6;
        *(float2*)(o1p + 0) = make_float2(o1[0], o1[1]);
        *(float2*)(o1p + 2) = make_float2(o1[2], o1[3]);
        *(float2*)(o1p + 4) = make_float2(o1[4], o1[5]);
    }
}

// ---------------------------------------------------------------------------
// Kernel 2: per-group statistics -> A0/B0 (out0 scale/shift), A1 (out1 scale).
// One block per group; binary search over sorted batch for the row range.
// ---------------------------------------------------------------------------
__global__ __launch_bounds__(384)
void k2_stats(const float* __restrict__ out, const int* __restrict__ batch,
              const float* __restrict__ mean_shift, const float* __restrict__ aw,
              const float* __restrict__ ab,
              float* __restrict__ A0, float* __restrict__ B0, float* __restrict__ A1)
{
    const int g = blockIdx.x;
    const int start = lower_bound_i(batch, N_ROWS, g);
    const int end   = lower_bound_i(batch, N_ROWS, g + 1);
    float cnt = (float)(end - start);
    if (cnt < 1.f) cnt = 1.f;
    const int t = threadIdx.x;

    if (t < M0) {
        float s = 0.f, q = 0.f;
        for (int n = start; n < end; ++n) {
            float v = out[(size_t)n * DIMX + t];
            s += v;
            q = fmaf(v, v, q);
        }
        float mean = s / cnt;
        float esq  = q / cnt;
        float ms   = mean_shift[t];
        float var  = esq - 2.f * ms * mean * mean + ms * ms * mean * mean;
        float sc   = rsqrtf(var + EPSV) * aw[t];
        A0[g * M0 + t] = sc;
        B0[g * M0 + t] = ab[t] - mean * ms * sc;
    } else {
        int w = t - M0;
        float q = 0.f;
        for (int n = start; n < end; ++n) {
            const float* p = out + (size_t)n * DIMX + M0 + w * 3;
            float a = p[0], b = p[1], c = p[2];
            q = fmaf(a, a, q); q = fmaf(b, b, q); q = fmaf(c, c, q);
        }
        float mq = q / (3.f * cnt);
        A1[g * M1 + w] = rsqrtf(mq + EPSV) * aw[M0 + w];
    }
}

// ---------------------------------------------------------------------------
// Kernel 3: apply normalization in place, float4-vectorized.
// ---------------------------------------------------------------------------
__global__ __launch_bounds__(256)
void k3_apply(float* __restrict__ out, const int* __restrict__ batch,
              const float* __restrict__ A0, const float* __restrict__ B0,
              const float* __restrict__ A1)
{
    const int total4 = N_ROWS * DIMX / 4;
    int idx = blockIdx.x * 256 + threadIdx.x;
    if (idx >= total4) return;
    int n  = idx / (DIMX / 4);
    int c4 = idx - n * (DIMX / 4);
    int c  = c4 * 4;
    int g  = batch[n];

    float4 v = ((float4*)out)[idx];
    if (c < M0) {
        float4 a = *(const float4*)(A0 + g * M0 + c);
        float4 b = *(const float4*)(B0 + g * M0 + c);
        v.x = fmaf(v.x, a.x, b.x);
        v.y = fmaf(v.y, a.y, b.y);
        v.z = fmaf(v.z, a.z, b.z);
        v.w = fmaf(v.w, a.w, b.w);
    } else {
        int e = c - M0;
        float r[4] = { v.x, v.y, v.z, v.w };
        #pragma unroll
        for (int j = 0; j < 4; ++j) {
            int w = (e + j) / 3;
            r[j] *= A1[g * M1 + w];
        }
        v = make_float4(r[0], r[1], r[2], r[3]);
    }
    ((float4*)out)[idx] = v;
}

// ---------------------------------------------------------------------------
extern "C" void kernel_launch(void* const* d_in, const int* in_sizes, int n_in,
                              void* d_out, int out_size, void* d_ws, size_t ws_size,
                              hipStream_t stream)
{
    const float* x     = (const float*)d_in[0];
    const float* y     = (const float*)d_in[1];
    const float* w000  = (const float*)d_in[2];
    const float* w011  = (const float*)d_in[3];
    const float* w101  = (const float*)d_in[4];
    const float* w110  = (const float*)d_in[5];
    const float* w111  = (const float*)d_in[6];
    const float* bias0 = (const float*)d_in[7];
    const float* mshift= (const float*)d_in[8];
    const float* aw    = (const float*)d_in[9];
    const float* ab    = (const float*)d_in[10];
    const int*   batch = (const int*)d_in[11];
    float* out = (float*)d_out;

    float* ws = (float*)d_ws;
    float* A0 = ws;                    // NG * 256
    float* B0 = A0 + NG * M0;          // NG * 256
    float* A1 = B0 + NG * M0;          // NG * 128

    k1_compute<<<N_ROWS / TM, 256, 0, stream>>>(x, y, w000, w011, w101, w110, w111, bias0, out);
    k2_stats<<<NG, 384, 0, stream>>>(out, batch, mshift, aw, ab, A0, B0, A1);
    const int total4 = N_ROWS * DIMX / 4;
    k3_apply<<<(total4 + 255) / 256, 256, 0, stream>>>(out, batch, A0, B0, A1);
}

// Round 2
// 553.534 us; speedup vs baseline: 2.1240x; 2.1240x over previous
//
#include <hip/hip_runtime.h>
#include <hip/hip_bf16.h>
#include <math.h>

#define N_ROWS 100000
#define NG     2000
#define M0     256
#define M1     128
#define DIMX   640
#define EPSV   1e-5f
#define BM     64

#define INV_SQRT3 0.57735026918962576f
#define INV_SQRT2 0.70710678118654752f

// packed bf16 weight layout in ws (element offsets)
#define OFF_W000T 0        // [256 cols][256 k]
#define OFF_W110T 65536    // [256 cols][128 k]
#define OFF_W011T 98304    // [128 cols][256 k]
#define OFF_W3T   131072   // [128 cols][256 k]  (k<128: w101, k>=128: w111*inv_sqrt2)
#define WT_TOTAL  163840

typedef __attribute__((ext_vector_type(8))) short bf16x8;
typedef __attribute__((ext_vector_type(4))) float f32x4;

__device__ __forceinline__ unsigned short f2bf(float f) {
    union { float f; unsigned int u; } v; v.f = f;
    unsigned int r = v.u + 0x7fff + ((v.u >> 16) & 1);
    return (unsigned short)(r >> 16);
}

__device__ __forceinline__ int lower_bound_i(const int* __restrict__ b, int n, int key) {
    int lo = 0, hi = n;
    while (lo < hi) { int m = (lo + hi) >> 1; if (b[m] < key) lo = m + 1; else hi = m; }
    return lo;
}

// ---------------------------------------------------------------------------
// k0: pack weights -> bf16, transposed (K-major per output col), scales folded.
// ---------------------------------------------------------------------------
__global__ __launch_bounds__(256)
void k0_pack(const float* __restrict__ w000, const float* __restrict__ w011,
             const float* __restrict__ w101, const float* __restrict__ w110,
             const float* __restrict__ w111, unsigned short* __restrict__ WT)
{
    int i = blockIdx.x * 256 + threadIdx.x;
    if (i < 65536) {
        int w = i >> 8, u = i & 255;
        WT[OFF_W000T + w * 256 + u] = f2bf(w000[u * 256 + w]);
    } else if (i < 98304) {
        int j = i - 65536; int w = j >> 7, u = j & 127;
        WT[OFF_W110T + w * 128 + u] = f2bf(w110[u * 256 + w]);
    } else if (i < 131072) {
        int j = i - 98304; int w = j >> 8, u = j & 255;
        WT[OFF_W011T + w * 256 + u] = f2bf(w011[u * 128 + w]);
    } else if (i < WT_TOTAL) {
        int j = i - 131072; int w = j >> 8, u = j & 255;
        float v = (u < 128) ? w101[u * 128 + w] : w111[(u - 128) * 128 + w] * INV_SQRT2;
        WT[OFF_W3T + w * 256 + u] = f2bf(v);
    }
}

// ---------------------------------------------------------------------------
// gemm phase: A (already in sA, bf16, K-contiguous rows) x Wp[col][k] -> acc.
// NK = K/32 steps, NF = N/16 col fragments. B double-buffered in LDS.
// ---------------------------------------------------------------------------
template<int NK, int NF>
__device__ __forceinline__ void gemm_phase(
    const unsigned short (&sA)[BM][264],
    unsigned short (&sB)[2][256][40],
    const unsigned short* __restrict__ Wp, const int Kel,
    f32x4* acc, const int t, const int wv, const int cb, const int kg)
{
    // stage k-step 0
    for (int idx = t; idx < NF * 16 * 4; idx += 256) {
        int c = idx >> 2, ch = idx & 3;
        *(bf16x8*)&sB[0][c][ch * 8] =
            *(const bf16x8*)(Wp + (size_t)c * Kel + ch * 8);
    }
    __syncthreads();
    int buf = 0;
    #pragma unroll
    for (int kk = 0; kk < NK; ++kk) {
        if (kk + 1 < NK) {
            for (int idx = t; idx < NF * 16 * 4; idx += 256) {
                int c = idx >> 2, ch = idx & 3;
                *(bf16x8*)&sB[buf ^ 1][c][ch * 8] =
                    *(const bf16x8*)(Wp + (size_t)c * Kel + (kk + 1) * 32 + ch * 8);
            }
        }
        bf16x8 af = *(const bf16x8*)&sA[wv * 16 + cb][kk * 32 + kg * 8];
        #pragma unroll
        for (int f = 0; f < NF; ++f) {
            bf16x8 bv = *(const bf16x8*)&sB[buf][f * 16 + cb][kg * 8];
            acc[f] = __builtin_amdgcn_mfma_f32_16x16x32_bf16(af, bv, acc[f], 0, 0, 0);
        }
        __syncthreads();
        buf ^= 1;
    }
}

// ---------------------------------------------------------------------------
// k1: per-row tensor product via bf16 MFMA. 64 rows/block, 4 waves (16 rows ea).
// ---------------------------------------------------------------------------
__global__ __launch_bounds__(256, 2)
void k1_mfma(const float* __restrict__ x, const float* __restrict__ y,
             const unsigned short* __restrict__ WT, const float* __restrict__ bias0,
             float* __restrict__ out)
{
    __shared__ unsigned short sA[BM][264];      // A tile (K<=256, +8 pad)
    __shared__ unsigned short sB[2][256][40];   // B K-step tiles, K-major
    __shared__ float sY[BM][4];

    const int t    = threadIdx.x;
    const int lane = t & 63;
    const int wv   = t >> 6;
    const int cb   = lane & 15;   // col (and A-row) within fragment
    const int kg   = lane >> 4;   // k-group 0..3
    const int n0   = blockIdx.x * BM;

    if (t < BM * 4) {
        int r = t >> 2;
        sY[r][t & 3] = (n0 + r < N_ROWS) ? y[(size_t)(n0 + r) * 4 + (t & 3)] : 0.f;
    }
    __syncthreads();

    // ---------------- out0: acc = (s1*s2)@W000 + (d/sqrt3)@W110 ----------------
    f32x4 acc0[16];
    #pragma unroll
    for (int f = 0; f < 16; ++f) acc0[f] = (f32x4){0.f, 0.f, 0.f, 0.f};

    // expansion: A = s1 * s2
    #pragma unroll
    for (int i = 0; i < 16; ++i) {
        int idx = i * 256 + t;
        int r = idx >> 6, c4 = idx & 63;
        int n = n0 + r;
        float4 v = make_float4(0.f, 0.f, 0.f, 0.f);
        if (n < N_ROWS) v = *(const float4*)(x + (size_t)n * DIMX + c4 * 4);
        float s = sY[r][0];
        ushort4 o;
        o.x = f2bf(v.x * s); o.y = f2bf(v.y * s);
        o.z = f2bf(v.z * s); o.w = f2bf(v.w * s);
        *(ushort4*)&sA[r][c4 * 4] = o;
    }
    gemm_phase<8, 16>(sA, sB, WT + OFF_W000T, 256, acc0, t, wv, cb, kg);

    // expansion: A = (v1 . v2) / sqrt3
    #pragma unroll
    for (int i = 0; i < 8; ++i) {
        int idx = i * 256 + t;
        int r = idx >> 5, q = idx & 31;
        int n = n0 + r;
        float4 a = make_float4(0,0,0,0), b = a, c = a;
        if (n < N_ROWS) {
            const float* vp = x + (size_t)n * DIMX + M0 + q * 12;
            a = *(const float4*)vp; b = *(const float4*)(vp + 4); c = *(const float4*)(vp + 8);
        }
        float v2x = sY[r][1], v2y = sY[r][2], v2z = sY[r][3];
        ushort4 o;
        o.x = f2bf((a.x * v2x + a.y * v2y + a.z * v2z) * INV_SQRT3);
        o.y = f2bf((a.w * v2x + b.x * v2y + b.y * v2z) * INV_SQRT3);
        o.z = f2bf((b.z * v2x + b.w * v2y + c.x * v2z) * INV_SQRT3);
        o.w = f2bf((c.y * v2x + c.z * v2y + c.w * v2z) * INV_SQRT3);
        *(ushort4*)&sA[r][q * 4] = o;
    }
    gemm_phase<4, 16>(sA, sB, WT + OFF_W110T, 128, acc0, t, wv, cb, kg);

    // epilogue: out0 = acc + bias0
    {
        int r0 = wv * 16 + kg * 4;
        #pragma unroll
        for (int f = 0; f < 16; ++f) {
            int col = f * 16 + cb;
            float bv = bias0[col];
            #pragma unroll
            for (int j = 0; j < 4; ++j) {
                int n = n0 + r0 + j;
                if (n < N_ROWS) out[(size_t)n * DIMX + col] = acc0[f][j] + bv;
            }
        }
    }

    // ---------------- out1: G2 = s1@W011 ; Hk = [v1k*s2, crossk]@[W101;W111/√2] ---
    f32x4 g2[8], h0[8], h1[8], h2[8];
    #pragma unroll
    for (int f = 0; f < 8; ++f) {
        g2[f] = (f32x4){0.f,0.f,0.f,0.f};
        h0[f] = (f32x4){0.f,0.f,0.f,0.f};
        h1[f] = (f32x4){0.f,0.f,0.f,0.f};
        h2[f] = (f32x4){0.f,0.f,0.f,0.f};
    }

    // expansion: A = s1 (raw)
    #pragma unroll
    for (int i = 0; i < 16; ++i) {
        int idx = i * 256 + t;
        int r = idx >> 6, c4 = idx & 63;
        int n = n0 + r;
        float4 v = make_float4(0.f, 0.f, 0.f, 0.f);
        if (n < N_ROWS) v = *(const float4*)(x + (size_t)n * DIMX + c4 * 4);
        ushort4 o;
        o.x = f2bf(v.x); o.y = f2bf(v.y); o.z = f2bf(v.z); o.w = f2bf(v.w);
        *(ushort4*)&sA[r][c4 * 4] = o;
    }
    gemm_phase<8, 8>(sA, sB, WT + OFF_W011T, 256, g2, t, wv, cb, kg);

    // k = 0,1,2: A = [v1k * s2 (u<128), cross_k (u>=128)]
    #pragma unroll
    for (int k = 0; k < 3; ++k) {
        const int k1 = (k + 1) % 3, k2 = (k + 2) % 3;
        #pragma unroll
        for (int i = 0; i < 8; ++i) {
            int idx = i * 256 + t;
            int r = idx >> 5, q = idx & 31;
            int n = n0 + r;
            float4 a = make_float4(0,0,0,0), b = a, c = a;
            if (n < N_ROWS) {
                const float* vp = x + (size_t)n * DIMX + M0 + q * 12;
                a = *(const float4*)vp; b = *(const float4*)(vp + 4); c = *(const float4*)(vp + 8);
            }
            float v1c[4][3] = { {a.x, a.y, a.z}, {a.w, b.x, b.y},
                                {b.z, b.w, c.x}, {c.y, c.z, c.w} };
            float s2v = sY[r][0];
            float v2a[3] = { sY[r][1], sY[r][2], sY[r][3] };
            ushort4 ov, oc;
            unsigned short* pv = (unsigned short*)&ov;
            unsigned short* pc = (unsigned short*)&oc;
            #pragma unroll
            for (int j = 0; j < 4; ++j) {
                pv[j] = f2bf(v1c[j][k] * s2v);
                pc[j] = f2bf(v1c[j][k1] * v2a[k2] - v1c[j][k2] * v2a[k1]);
            }
            *(ushort4*)&sA[r][q * 4]       = ov;
            *(ushort4*)&sA[r][128 + q * 4] = oc;
        }
        if (k == 0)      gemm_phase<8, 8>(sA, sB, WT + OFF_W3T, 256, h0, t, wv, cb, kg);
        else if (k == 1) gemm_phase<8, 8>(sA, sB, WT + OFF_W3T, 256, h1, t, wv, cb, kg);
        else             gemm_phase<8, 8>(sA, sB, WT + OFF_W3T, 256, h2, t, wv, cb, kg);
    }

    // epilogue: out1[n][w][k] = v2k * G2 + Hk   (interleaved layout 256 + 3w + k)
    {
        int r0 = wv * 16 + kg * 4;
        #pragma unroll
        for (int f = 0; f < 8; ++f) {
            int w = f * 16 + cb;
            #pragma unroll
            for (int j = 0; j < 4; ++j) {
                int r = r0 + j;
                int n = n0 + r;
                if (n < N_ROWS) {
                    float g = g2[f][j];
                    float* p = out + (size_t)n * DIMX + M0 + 3 * w;
                    p[0] = fmaf(sY[r][1], g, h0[f][j]);
                    p[1] = fmaf(sY[r][2], g, h1[f][j]);
                    p[2] = fmaf(sY[r][3], g, h2[f][j]);
                }
            }
        }
    }
}

// ---------------------------------------------------------------------------
// k2: per-group statistics (unchanged, correctness-proven)
// ---------------------------------------------------------------------------
__global__ __launch_bounds__(384)
void k2_stats(const float* __restrict__ out, const int* __restrict__ batch,
              const float* __restrict__ mean_shift, const float* __restrict__ aw,
              const float* __restrict__ ab,
              float* __restrict__ A0, float* __restrict__ B0, float* __restrict__ A1)
{
    const int g = blockIdx.x;
    const int start = lower_bound_i(batch, N_ROWS, g);
    const int end   = lower_bound_i(batch, N_ROWS, g + 1);
    float cnt = (float)(end - start);
    if (cnt < 1.f) cnt = 1.f;
    const int t = threadIdx.x;

    if (t < M0) {
        float s = 0.f, q = 0.f;
        for (int n = start; n < end; ++n) {
            float v = out[(size_t)n * DIMX + t];
            s += v;
            q = fmaf(v, v, q);
        }
        float mean = s / cnt;
        float esq  = q / cnt;
        float ms   = mean_shift[t];
        float var  = esq - 2.f * ms * mean * mean + ms * ms * mean * mean;
        float sc   = rsqrtf(var + EPSV) * aw[t];
        A0[g * M0 + t] = sc;
        B0[g * M0 + t] = ab[t] - mean * ms * sc;
    } else {
        int w = t - M0;
        float q = 0.f;
        for (int n = start; n < end; ++n) {
            const float* p = out + (size_t)n * DIMX + M0 + w * 3;
            float a = p[0], b = p[1], c = p[2];
            q = fmaf(a, a, q); q = fmaf(b, b, q); q = fmaf(c, c, q);
        }
        float mq = q / (3.f * cnt);
        A1[g * M1 + w] = rsqrtf(mq + EPSV) * aw[M0 + w];
    }
}

// ---------------------------------------------------------------------------
// k3: apply normalization in place (unchanged)
// ---------------------------------------------------------------------------
__global__ __launch_bounds__(256)
void k3_apply(float* __restrict__ out, const int* __restrict__ batch,
              const float* __restrict__ A0, const float* __restrict__ B0,
              const float* __restrict__ A1)
{
    const int total4 = N_ROWS * DIMX / 4;
    int idx = blockIdx.x * 256 + threadIdx.x;
    if (idx >= total4) return;
    int n  = idx / (DIMX / 4);
    int c4 = idx - n * (DIMX / 4);
    int c  = c4 * 4;
    int g  = batch[n];

    float4 v = ((float4*)out)[idx];
    if (c < M0) {
        float4 a = *(const float4*)(A0 + g * M0 + c);
        float4 b = *(const float4*)(B0 + g * M0 + c);
        v.x = fmaf(v.x, a.x, b.x);
        v.y = fmaf(v.y, a.y, b.y);
        v.z = fmaf(v.z, a.z, b.z);
        v.w = fmaf(v.w, a.w, b.w);
    } else {
        int e = c - M0;
        float r[4] = { v.x, v.y, v.z, v.w };
        #pragma unroll
        for (int j = 0; j < 4; ++j) {
            int w = (e + j) / 3;
            r[j] *= A1[g * M1 + w];
        }
        v = make_float4(r[0], r[1], r[2], r[3]);
    }
    ((float4*)out)[idx] = v;
}

// ---------------------------------------------------------------------------
extern "C" void kernel_launch(void* const* d_in, const int* in_sizes, int n_in,
                              void* d_out, int out_size, void* d_ws, size_t ws_size,
                              hipStream_t stream)
{
    const float* x     = (const float*)d_in[0];
    const float* y     = (const float*)d_in[1];
    const float* w000  = (const float*)d_in[2];
    const float* w011  = (const float*)d_in[3];
    const float* w101  = (const float*)d_in[4];
    const float* w110  = (const float*)d_in[5];
    const float* w111  = (const float*)d_in[6];
    const float* bias0 = (const float*)d_in[7];
    const float* mshift= (const float*)d_in[8];
    const float* aw    = (const float*)d_in[9];
    const float* ab    = (const float*)d_in[10];
    const int*   batch = (const int*)d_in[11];
    float* out = (float*)d_out;

    unsigned short* WT = (unsigned short*)d_ws;
    float* fws = (float*)((char*)d_ws + WT_TOTAL * sizeof(unsigned short));
    float* A0 = fws;                   // NG * 256
    float* B0 = A0 + NG * M0;          // NG * 256
    float* A1 = B0 + NG * M0;          // NG * 128

    k0_pack<<<(WT_TOTAL + 255) / 256, 256, 0, stream>>>(w000, w011, w101, w110, w111, WT);
    k1_mfma<<<(N_ROWS + BM - 1) / BM, 256, 0, stream>>>(x, y, WT, bias0, out);
    k2_stats<<<NG, 384, 0, stream>>>(out, batch, mshift, aw, ab, A0, B0, A1);
    const int total4 = N_ROWS * DIMX / 4;
    k3_apply<<<(total4 + 255) / 256, 256, 0, stream>>>(out, batch, A0, B0, A1);
}

// Round 3
// 409.997 us; speedup vs baseline: 2.8676x; 1.3501x over previous
//
#include <hip/hip_runtime.h>
#include <math.h>

#define N_ROWS 100000
#define NG     2000
#define M0     256
#define M1     128
#define DIMX   640
#define EPSV   1e-5f
#define BM     32

#define INV_SQRT3 0.57735026918962576f
#define INV_SQRT2 0.70710678118654752f

// packed B regions (ushort element offsets). Tile = 1KB = 512 ushorts,
// layout: [frag f][kstep kk][lane 0..63][e 0..7] matching the MFMA B operand
// (lane l holds col = f*16 + (l&15), k = kk*32 + (l>>4)*8 + e).
#define OFF_U  0         // cols 384 = [W000 | W011], K=256   (24 frags x 8 ksteps)
#define OFF_D  98304     // cols 256 = W110 * 1/sqrt3, K=128  (16 frags x 4 ksteps)
#define OFF_V  131072    // cols 256 = [W101 | W111/sqrt2], K=128
#define WT_TOTAL 163840

typedef __attribute__((ext_vector_type(8))) short bf16x8;
typedef __attribute__((ext_vector_type(4))) float f32x4;

__device__ __forceinline__ unsigned short f2bf(float f) {
    union { float f; unsigned int u; } v; v.f = f;
    unsigned int r = v.u + 0x7fff + ((v.u >> 16) & 1);
    return (unsigned short)(r >> 16);
}
__device__ __forceinline__ float bf2f(unsigned short u) {
    union { unsigned int u; float f; } v; v.u = ((unsigned int)u) << 16; return v.f;
}

__device__ __forceinline__ int lower_bound_i(const int* __restrict__ b, int n, int key) {
    int lo = 0, hi = n;
    while (lo < hi) { int m = (lo + hi) >> 1; if (b[m] < key) lo = m + 1; else hi = m; }
    return lo;
}

// ---------------------------------------------------------------------------
// k0: pack weights -> bf16 per-MFMA-tile layout, scales folded.
// ---------------------------------------------------------------------------
__global__ __launch_bounds__(256)
void k0_pack(const float* __restrict__ w000, const float* __restrict__ w011,
             const float* __restrict__ w101, const float* __restrict__ w110,
             const float* __restrict__ w111, unsigned short* __restrict__ WT)
{
    int i = blockIdx.x * 256 + threadIdx.x;
    if (i >= WT_TOTAL) return;
    int l = (i >> 3) & 63, e = i & 7;
    int lc = l & 15, lk = (l >> 4) << 3;
    float val;
    if (i < OFF_D) {
        int tile = i >> 9; int f = tile >> 3, kk = tile & 7;
        int col = f * 16 + lc, k = kk * 32 + lk + e;
        val = (col < 256) ? w000[k * 256 + col] : w011[k * 128 + (col - 256)];
    } else if (i < OFF_V) {
        int j = i - OFF_D; int tile = j >> 9; int f = tile >> 2, kk = tile & 3;
        int col = f * 16 + lc, k = kk * 32 + lk + e;
        val = w110[k * 256 + col] * INV_SQRT3;
    } else {
        int j = i - OFF_V; int tile = j >> 9; int f = tile >> 2, kk = tile & 3;
        int col = f * 16 + lc, k = kk * 32 + lk + e;
        val = (col < 128) ? w101[k * 128 + col]
                          : w111[k * 128 + (col - 128)] * INV_SQRT2;
    }
    WT[i] = f2bf(val);
}

// A-fragment read from swizzled LDS: row stride KW ushorts, 16B-slot XOR swizzle.
__device__ __forceinline__ bf16x8 ldA(const unsigned short* base, int KW,
                                      int row, int kk, int kg)
{
    int off = row * KW + (((kk << 5) + (kg << 3)) ^ ((row & 7) << 3));
    return *(const bf16x8*)(base + off);
}

// ---------------------------------------------------------------------------
// k1: 32 rows/block, 4 waves; each wave owns a column quarter and 2 row-frags.
// A-matrices are raw x slices in swizzled LDS; y-scalars applied post-GEMM.
// B tiles are loaded per-lane straight from L2 (packed layout), no barriers
// inside any GEMM loop.
// ---------------------------------------------------------------------------
__global__ __launch_bounds__(256, 2)
void k1_mfma(const float* __restrict__ x, const float* __restrict__ y,
             const unsigned short* __restrict__ WT, const float* __restrict__ bias0,
             float* __restrict__ out)
{
    __shared__ unsigned short xs1[BM][256];     // s1 (bf16, swizzled)
    __shared__ unsigned short xv[3][BM][128];   // v1 components (deinterleaved)
    __shared__ unsigned short xd[BM][128];      // d = v1 . v2
    __shared__ float sY[BM][4];
    __shared__ float sBias[256];

    const int t    = threadIdx.x;
    const int lane = t & 63;
    const int wv   = t >> 6;
    const int cb   = lane & 15;
    const int kg   = lane >> 4;
    const int n0   = blockIdx.x * BM;   // N_ROWS = 3125 * 32 exactly

    if (t < 128) sY[t >> 2][t & 3] = y[(size_t)(n0 + (t >> 2)) * 4 + (t & 3)];
    sBias[t] = bias0[t];

    // ---- stage x once: s1 and deinterleaved v1 ----
    #pragma unroll
    for (int i = 0; i < 8; ++i) {
        int idx = i * 256 + t;
        int r = idx >> 6, c4 = idx & 63;
        float4 v = *(const float4*)(x + (size_t)(n0 + r) * DIMX + c4 * 4);
        ushort4 o = { f2bf(v.x), f2bf(v.y), f2bf(v.z), f2bf(v.w) };
        *(ushort4*)&xs1[r][(c4 * 4) ^ ((r & 7) << 3)] = o;
    }
    #pragma unroll
    for (int i = 0; i < 4; ++i) {
        int idx = i * 256 + t;
        int r = idx >> 5, q = idx & 31;
        const float* vp = x + (size_t)(n0 + r) * DIMX + M0 + q * 12;
        float4 a = *(const float4*)vp;
        float4 b = *(const float4*)(vp + 4);
        float4 c = *(const float4*)(vp + 8);
        int off = (q * 4) ^ ((r & 7) << 3);
        ushort4 ox = { f2bf(a.x), f2bf(a.w), f2bf(b.z), f2bf(c.y) };
        ushort4 oy = { f2bf(a.y), f2bf(b.x), f2bf(b.w), f2bf(c.z) };
        ushort4 oz = { f2bf(a.z), f2bf(b.y), f2bf(c.x), f2bf(c.w) };
        *(ushort4*)&xv[0][r][off] = ox;
        *(ushort4*)&xv[1][r][off] = oy;
        *(ushort4*)&xv[2][r][off] = oz;
    }
    __syncthreads();

    // ---- d = v1 . v2 (from LDS, bf16 in / bf16 out) ----
    #pragma unroll
    for (int i = 0; i < 4; ++i) {
        int idx = i * 256 + t;
        int r = idx >> 5, q = idx & 31;
        int off = (q * 4) ^ ((r & 7) << 3);
        ushort4 ux = *(const ushort4*)&xv[0][r][off];
        ushort4 uy = *(const ushort4*)&xv[1][r][off];
        ushort4 uz = *(const ushort4*)&xv[2][r][off];
        float v2x = sY[r][1], v2y = sY[r][2], v2z = sY[r][3];
        ushort4 od;
        od.x = f2bf(bf2f(ux.x) * v2x + bf2f(uy.x) * v2y + bf2f(uz.x) * v2z);
        od.y = f2bf(bf2f(ux.y) * v2x + bf2f(uy.y) * v2y + bf2f(uz.y) * v2z);
        od.z = f2bf(bf2f(ux.z) * v2x + bf2f(uy.z) * v2y + bf2f(uz.z) * v2z);
        od.w = f2bf(bf2f(ux.w) * v2x + bf2f(uy.w) * v2y + bf2f(uz.w) * v2z);
        *(ushort4*)&xd[r][off] = od;
    }
    __syncthreads();

    // per-lane row scalars (rows rg*16 + kg*4 + j)
    float s2v[2][4];
    #pragma unroll
    for (int rg = 0; rg < 2; ++rg)
        #pragma unroll
        for (int j = 0; j < 4; ++j)
            s2v[rg][j] = sY[rg * 16 + kg * 4 + j][0];

    // ---- U phase: [out0_raw | G2] = s1 @ [W000 | W011], K=256 ----
    f32x4 aO[4][2];   // out0 cols wv*64 + q*16
    f32x4 aG[2][2];   // G2 cols wv*32 + q*16
    #pragma unroll
    for (int q = 0; q < 4; ++q) { aO[q][0] = (f32x4){0,0,0,0}; aO[q][1] = (f32x4){0,0,0,0}; }
    #pragma unroll
    for (int q = 0; q < 2; ++q) { aG[q][0] = (f32x4){0,0,0,0}; aG[q][1] = (f32x4){0,0,0,0}; }

    #pragma unroll
    for (int kk = 0; kk < 8; ++kk) {
        bf16x8 a0 = ldA(&xs1[0][0], 256, cb, kk, kg);
        bf16x8 a1 = ldA(&xs1[0][0], 256, 16 + cb, kk, kg);
        #pragma unroll
        for (int q = 0; q < 6; ++q) {
            int f = (q < 4) ? (wv * 4 + q) : (16 + wv * 2 + (q - 4));
            bf16x8 b = *(const bf16x8*)(WT + OFF_U + (size_t)(f * 8 + kk) * 512 + lane * 8);
            if (q < 4) {
                aO[q][0] = __builtin_amdgcn_mfma_f32_16x16x32_bf16(a0, b, aO[q][0], 0, 0, 0);
                aO[q][1] = __builtin_amdgcn_mfma_f32_16x16x32_bf16(a1, b, aO[q][1], 0, 0, 0);
            } else {
                aG[q - 4][0] = __builtin_amdgcn_mfma_f32_16x16x32_bf16(a0, b, aG[q - 4][0], 0, 0, 0);
                aG[q - 4][1] = __builtin_amdgcn_mfma_f32_16x16x32_bf16(a1, b, aG[q - 4][1], 0, 0, 0);
            }
        }
    }

    // scale out0 by s2 (post-GEMM), then accumulate D = d @ W110'
    #pragma unroll
    for (int q = 0; q < 4; ++q)
        #pragma unroll
        for (int rg = 0; rg < 2; ++rg)
            #pragma unroll
            for (int j = 0; j < 4; ++j)
                aO[q][rg][j] *= s2v[rg][j];

    #pragma unroll
    for (int kk = 0; kk < 4; ++kk) {
        bf16x8 a0 = ldA(&xd[0][0], 128, cb, kk, kg);
        bf16x8 a1 = ldA(&xd[0][0], 128, 16 + cb, kk, kg);
        #pragma unroll
        for (int q = 0; q < 4; ++q) {
            int f = wv * 4 + q;
            bf16x8 b = *(const bf16x8*)(WT + OFF_D + (size_t)(f * 4 + kk) * 512 + lane * 8);
            aO[q][0] = __builtin_amdgcn_mfma_f32_16x16x32_bf16(a0, b, aO[q][0], 0, 0, 0);
            aO[q][1] = __builtin_amdgcn_mfma_f32_16x16x32_bf16(a1, b, aO[q][1], 0, 0, 0);
        }
    }

    // out0 epilogue
    #pragma unroll
    for (int q = 0; q < 4; ++q) {
        int col = wv * 64 + q * 16 + cb;
        float bb = sBias[col];
        #pragma unroll
        for (int rg = 0; rg < 2; ++rg)
            #pragma unroll
            for (int j = 0; j < 4; ++j) {
                int row = rg * 16 + kg * 4 + j;
                out[(size_t)(n0 + row) * DIMX + col] = aO[q][rg][j] + bb;
            }
    }

    // ---- V phase: [P | Q]_j = v1_j @ [W101 | W111/sqrt2], K=128, j=0..2 ----
    f32x4 aV[4][3][2];   // q: 0,1 = P frags; 2,3 = Q frags
    #pragma unroll
    for (int q = 0; q < 4; ++q)
        #pragma unroll
        for (int j = 0; j < 3; ++j) { aV[q][j][0] = (f32x4){0,0,0,0}; aV[q][j][1] = (f32x4){0,0,0,0}; }

    #pragma unroll
    for (int kk = 0; kk < 4; ++kk) {
        bf16x8 av[3][2];
        #pragma unroll
        for (int j = 0; j < 3; ++j) {
            av[j][0] = ldA(&xv[j][0][0], 128, cb, kk, kg);
            av[j][1] = ldA(&xv[j][0][0], 128, 16 + cb, kk, kg);
        }
        #pragma unroll
        for (int q = 0; q < 4; ++q) {
            int f = (q < 2) ? (wv * 2 + q) : (8 + wv * 2 + (q - 2));
            bf16x8 b = *(const bf16x8*)(WT + OFF_V + (size_t)(f * 4 + kk) * 512 + lane * 8);
            #pragma unroll
            for (int j = 0; j < 3; ++j) {
                aV[q][j][0] = __builtin_amdgcn_mfma_f32_16x16x32_bf16(av[j][0], b, aV[q][j][0], 0, 0, 0);
                aV[q][j][1] = __builtin_amdgcn_mfma_f32_16x16x32_bf16(av[j][1], b, aV[q][j][1], 0, 0, 0);
            }
        }
    }

    // out1 epilogue: out1[n][3w+k] = v2k*G2 + s2*Pk + v2_{k2}*Q_{k1} - v2_{k1}*Q_{k2}
    #pragma unroll
    for (int f2 = 0; f2 < 2; ++f2) {
        int w = wv * 32 + f2 * 16 + cb;
        #pragma unroll
        for (int rg = 0; rg < 2; ++rg)
            #pragma unroll
            for (int j = 0; j < 4; ++j) {
                int row = rg * 16 + kg * 4 + j;
                int n = n0 + row;
                float g   = aG[f2][rg][j];
                float s2r = sY[row][0];
                float w2x = sY[row][1], w2y = sY[row][2], w2z = sY[row][3];
                float P0 = aV[f2][0][rg][j], P1 = aV[f2][1][rg][j], P2 = aV[f2][2][rg][j];
                float Q0 = aV[2 + f2][0][rg][j], Q1 = aV[2 + f2][1][rg][j], Q2 = aV[2 + f2][2][rg][j];
                float e0 = w2x * g + s2r * P0 + w2z * Q1 - w2y * Q2;
                float e1 = w2y * g + s2r * P1 + w2x * Q2 - w2z * Q0;
                float e2 = w2z * g + s2r * P2 + w2y * Q0 - w2x * Q1;
                float* p = out + (size_t)n * DIMX + M0 + 3 * w;
                *(float2*)p = make_float2(e0, e1);
                p[2] = e2;
            }
    }
}

// ---------------------------------------------------------------------------
// k2: per-group statistics (unchanged)
// ---------------------------------------------------------------------------
__global__ __launch_bounds__(384)
void k2_stats(const float* __restrict__ out, const int* __restrict__ batch,
              const float* __restrict__ mean_shift, const float* __restrict__ aw,
              const float* __restrict__ ab,
              float* __restrict__ A0, float* __restrict__ B0, float* __restrict__ A1)
{
    const int g = blockIdx.x;
    const int start = lower_bound_i(batch, N_ROWS, g);
    const int end   = lower_bound_i(batch, N_ROWS, g + 1);
    float cnt = (float)(end - start);
    if (cnt < 1.f) cnt = 1.f;
    const int t = threadIdx.x;

    if (t < M0) {
        float s = 0.f, q = 0.f;
        for (int n = start; n < end; ++n) {
            float v = out[(size_t)n * DIMX + t];
            s += v;
            q = fmaf(v, v, q);
        }
        float mean = s / cnt;
        float esq  = q / cnt;
        float ms   = mean_shift[t];
        float var  = esq - 2.f * ms * mean * mean + ms * ms * mean * mean;
        float sc   = rsqrtf(var + EPSV) * aw[t];
        A0[g * M0 + t] = sc;
        B0[g * M0 + t] = ab[t] - mean * ms * sc;
    } else {
        int w = t - M0;
        float q = 0.f;
        for (int n = start; n < end; ++n) {
            const float* p = out + (size_t)n * DIMX + M0 + w * 3;
            float a = p[0], b = p[1], c = p[2];
            q = fmaf(a, a, q); q = fmaf(b, b, q); q = fmaf(c, c, q);
        }
        float mq = q / (3.f * cnt);
        A1[g * M1 + w] = rsqrtf(mq + EPSV) * aw[M0 + w];
    }
}

// ---------------------------------------------------------------------------
// k3: apply normalization in place (unchanged)
// ---------------------------------------------------------------------------
__global__ __launch_bounds__(256)
void k3_apply(float* __restrict__ out, const int* __restrict__ batch,
              const float* __restrict__ A0, const float* __restrict__ B0,
              const float* __restrict__ A1)
{
    const int total4 = N_ROWS * DIMX / 4;
    int idx = blockIdx.x * 256 + threadIdx.x;
    if (idx >= total4) return;
    int n  = idx / (DIMX / 4);
    int c4 = idx - n * (DIMX / 4);
    int c  = c4 * 4;
    int g  = batch[n];

    float4 v = ((float4*)out)[idx];
    if (c < M0) {
        float4 a = *(const float4*)(A0 + g * M0 + c);
        float4 b = *(const float4*)(B0 + g * M0 + c);
        v.x = fmaf(v.x, a.x, b.x);
        v.y = fmaf(v.y, a.y, b.y);
        v.z = fmaf(v.z, a.z, b.z);
        v.w = fmaf(v.w, a.w, b.w);
    } else {
        int e = c - M0;
        float r[4] = { v.x, v.y, v.z, v.w };
        #pragma unroll
        for (int j = 0; j < 4; ++j) {
            int w = (e + j) / 3;
            r[j] *= A1[g * M1 + w];
        }
        v = make_float4(r[0], r[1], r[2], r[3]);
    }
    ((float4*)out)[idx] = v;
}

// ---------------------------------------------------------------------------
extern "C" void kernel_launch(void* const* d_in, const int* in_sizes, int n_in,
                              void* d_out, int out_size, void* d_ws, size_t ws_size,
                              hipStream_t stream)
{
    const float* x     = (const float*)d_in[0];
    const float* y     = (const float*)d_in[1];
    const float* w000  = (const float*)d_in[2];
    const float* w011  = (const float*)d_in[3];
    const float* w101  = (const float*)d_in[4];
    const float* w110  = (const float*)d_in[5];
    const float* w111  = (const float*)d_in[6];
    const float* bias0 = (const float*)d_in[7];
    const float* mshift= (const float*)d_in[8];
    const float* aw    = (const float*)d_in[9];
    const float* ab    = (const float*)d_in[10];
    const int*   batch = (const int*)d_in[11];
    float* out = (float*)d_out;

    unsigned short* WT = (unsigned short*)d_ws;
    float* fws = (float*)((char*)d_ws + WT_TOTAL * sizeof(unsigned short));
    float* A0 = fws;                   // NG * 256
    float* B0 = A0 + NG * M0;          // NG * 256
    float* A1 = B0 + NG * M0;          // NG * 128

    k0_pack<<<WT_TOTAL / 256, 256, 0, stream>>>(w000, w011, w101, w110, w111, WT);
    k1_mfma<<<N_ROWS / BM, 256, 0, stream>>>(x, y, WT, bias0, out);
    k2_stats<<<NG, 384, 0, stream>>>(out, batch, mshift, aw, ab, A0, B0, A1);
    const int total4 = N_ROWS * DIMX / 4;
    k3_apply<<<(total4 + 255) / 256, 256, 0, stream>>>(out, batch, A0, B0, A1);
}